// Round 8
// baseline (2442.015 us; speedup 1.0000x reference)
//
#include <hip/hip_runtime.h>
#include <hip/hip_bf16.h>

// ---------------------------------------------------------------------------
// CharRNN: emb -> 4x conv1d(SAME) -> concat -> GRU(256) last state.
//
// Algebraic restructure (conv+Wx+emb linear in one-hot token):
//   xw[b,t,:] = beff + sum_{d=0..4} EmbW[d][X[b,t+d-2]][:]   (f32 tables)
//
// R8: R6/R7 showed VGPR_Count=128 regardless of __launch_bounds__ — the LLVM
// scheduler's occupancy heuristic set a 128-reg budget and spilled all 48 Bf
// fragments (cold-dispatch 32ms scratch-alloc signature + ~10k cyc/step
// steady = L2-cached scratch reloads). launch_bounds only CAPS the budget.
// Fix: __attribute__((amdgpu_waves_per_eu(2,2))) pins budget to 256 regs;
// gather moved after bar0 so n1/n2 don't overlap acc[6] (peak ~230/256).
// Numerics identical to R5-R7 (split-bf16 h hi/lo, f32 tables, bf16 Wh).
// ---------------------------------------------------------------------------

typedef float f32x4 __attribute__((ext_vector_type(4)));
typedef short s16x8 __attribute__((ext_vector_type(8)));
typedef unsigned short u16;
typedef unsigned int   u32;

// ws byte offsets
#define OFF_WC    0u         // f32  [5][64][768]
#define OFF_EMBW  983040u    // f32  [5][128][768]
#define OFF_BEFF  2949120u   // f32  [768]
#define OFF_WHP   2952192u   // bf16 [768][256] (Wh^T)
#define OFF_MODE  3345408u   // int  (0 = bf16 storage, 1 = f32 storage)
#define WS_NEED   3345472u

__device__ __forceinline__ float bf2f(u16 v){
  unsigned u = ((unsigned)v) << 16; return __builtin_bit_cast(float, u);
}
__device__ __forceinline__ u16 f2bf(float f){
  unsigned u = __builtin_bit_cast(unsigned, f);
  unsigned r = u + 0x7FFFu + ((u >> 16) & 1u);
  return (u16)(r >> 16);
}
__device__ __forceinline__ float ldv(const void* p, int i, int m){
  return m ? ((const float*)p)[i] : bf2f(((const u16*)p)[i]);
}

// ---- probe: detect storage dtype of emb_table ----
__global__ void k_probe(const void* __restrict__ emb, char* ws){
  const u16* w = (const u16*)emb;
  const int ln = threadIdx.x;
  bool bad = false;
  for (int j = 0; j < 8; ++j){
    u16 v = w[ln*8 + j];
    if (((v >> 7) & 0xFF) >= 0x86) bad = true;  // |bf16| >= 2^7: impossible for emb
  }
  unsigned long long m = __ballot(bad);
  if (ln == 0) *(int*)(ws + OFF_MODE) = (__popcll(m) > 4) ? 1 : 0;
}

// ---- Wc[d][e][j] = sum_br sum_c w_br[d-2+pad][e][c] * Wx[off_br+c][j] ----
__global__ void k_wc(const void* __restrict__ w2, const void* __restrict__ w3,
                     const void* __restrict__ w4, const void* __restrict__ w5,
                     const void* __restrict__ Wx, char* ws){
  const int md = *(const int*)(ws + OFF_MODE);
  const int d = blockIdx.x >> 6;
  const int e = blockIdx.x & 63;
  const int j0 = threadIdx.x;
  const void* wv[4] = {w2,w3,w4,w5};
  const int Kk[4] = {2,3,4,5}, pd[4] = {0,1,1,2};
  float a0=0.f, a1=0.f, a2=0.f;
  for (int br=0; br<4; ++br){
    int k = d - 2 + pd[br];
    if (k < 0 || k >= Kk[br]) continue;
    const int wbase  = (k*64 + e)*128;
    const int wxbase = (br*128)*768;
    for (int c=0; c<128; ++c){
      float wcv = ldv(wv[br], wbase + c, md);
      a0 += wcv * ldv(Wx, wxbase + c*768 + j0      , md);
      a1 += wcv * ldv(Wx, wxbase + c*768 + j0 + 256, md);
      a2 += wcv * ldv(Wx, wxbase + c*768 + j0 + 512, md);
    }
  }
  float* o = (float*)(ws + OFF_WC) + (d*64 + e)*768;
  o[j0] = a0; o[j0+256] = a1; o[j0+512] = a2;
}

// ---- beff[j] = b_in[j] + sum_br sum_c b_br[c]*Wx[off+c][j] ----
__global__ void k_beff(const void* __restrict__ b2, const void* __restrict__ b3,
                       const void* __restrict__ b4, const void* __restrict__ b5,
                       const void* __restrict__ Wx, const void* __restrict__ bin,
                       char* ws){
  const int md = *(const int*)(ws + OFF_MODE);
  int j = blockIdx.x*256 + threadIdx.x;
  if (j >= 768) return;
  const void* bv[4] = {b2,b3,b4,b5};
  float acc = ldv(bin, j, md);
  for (int br=0; br<4; ++br)
    for (int c=0; c<128; ++c)
      acc += ldv(bv[br], c, md) * ldv(Wx, (br*128 + c)*768 + j, md);
  ((float*)(ws + OFF_BEFF))[j] = acc;
}

// ---- EmbW[d][ch][j] = sum_e emb[ch][e] * Wc[d][e][j]  (f32 out) ----
__global__ void k_embw(const void* __restrict__ emb, char* ws){
  const int md = *(const int*)(ws + OFF_MODE);
  const int d = blockIdx.x >> 7, ch = blockIdx.x & 127;
  const float* wc = (const float*)(ws + OFF_WC) + d*64*768;
  float* ew = (float*)(ws + OFF_EMBW) + (size_t)(d*128 + ch)*768;
  const int j0 = threadIdx.x;
  float a0=0.f, a1=0.f, a2=0.f;
  for (int e=0; e<64; ++e){
    float ev = ldv(emb, ch*64 + e, md);
    a0 += ev*wc[e*768 + j0      ];
    a1 += ev*wc[e*768 + j0 + 256];
    a2 += ev*wc[e*768 + j0 + 512];
  }
  ew[j0] = a0; ew[j0+256] = a1; ew[j0+512] = a2;
}

// ---- whp[j][k] = Wh[k][j]  (bf16 out) ----
__global__ void k_whp(const void* __restrict__ Wh, char* ws){
  const int md = *(const int*)(ws + OFF_MODE);
  const int j = blockIdx.x, k = threadIdx.x;
  ((u16*)(ws + OFF_WHP))[j*256 + k] = f2bf(ldv(Wh, k*768 + j, md));
}

// ---- GRU: 32 blocks (4 batch rows each) x 512 threads (8 waves) ----
__launch_bounds__(512)
__attribute__((amdgpu_waves_per_eu(2, 2)))
__global__ void k_gru(const int* __restrict__ X, const void* __restrict__ brec,
                      const char* __restrict__ ws, void* __restrict__ outv){
  const int tid = threadIdx.x;
  const int wv  = tid >> 6, ln = tid & 63;
  const int l15 = ln & 15, l4 = ln >> 4;
  const int g = blockIdx.x;

  const int md = *(const int*)(ws + OFF_MODE);
  const float* embw = (const float*)(ws + OFF_EMBW);
  const float* beff = (const float*)(ws + OFF_BEFF);
  const u16*   whp  = (const u16*)(ws + OFF_WHP);

  __shared__ u16   hbuf[16*272];       // [par(2)][hi/lo(2)][brow(4)][272] swz
  __shared__ float xwlds[2][4][772];   // [buf][brow][768+swz]
  __shared__ float hwlds[4][772];

  // persistent Wh B-frags: wave owns tiles t = wv*6 + i, cols t*16 + l15
  s16x8 Bf[6][8];
  #pragma unroll
  for (int i=0; i<6; ++i){
    const int col = (wv*6 + i)*16 + l15;
    #pragma unroll
    for (int q=0; q<8; ++q)
      Bf[i][q] = *(const s16x8*)(whp + col*256 + q*32 + l4*8);
  }

  // ---- gate-side assignment: units (row1,hcol) and (row1+2,hcol) ----
  const int hcol = tid & 255;
  const int row1 = tid >> 8;           // 0..1; second unit row = row1+2
  const float br0 = ldv(brec,       hcol, md);
  const float br1 = ldv(brec, 256 + hcol, md);
  const float br2 = ldv(brec, 512 + hcol, md);
  const int gsw  = ((hcol>>6)&1)<<4;   // xw/hw lds swizzle for this col
  const int ksw  = ((hcol>>6)&1)<<5;   // hbuf k-swizzle for this col

  // ---- gather-side assignment ----
  const int grow  = wv >> 1;                            // gather row 0..3
  const int heavy = (((wv & 1) ^ ((wv >> 2) & 1)) == 0);// SIMD-balanced
  const int c1 = heavy ? ln : 64 + ln;                  // chunk in [0,192)
  const int c2 = 128 + ln;                              // heavy only
  const int bbase = (g*4 + grow)*512;

  for (int i = tid; i < 2176; i += 512) ((u32*)hbuf)[i] = 0u;

  // prologue: xw(0) -> xwlds[0]  (taps d=2..4 -> t=0..2)
  {
    f32x4 v1 = *(const f32x4*)(beff + c1*4);
    f32x4 v2 = heavy ? *(const f32x4*)(beff + c2*4) : (f32x4){0.f,0.f,0.f,0.f};
    #pragma unroll
    for (int d=2; d<5; ++d){
      const int ch = X[bbase + (d-2)] & 127;
      const float* tp = embw + (size_t)(d*128 + ch)*768;
      v1 += *(const f32x4*)(tp + c1*4);
      if (heavy) v2 += *(const f32x4*)(tp + c2*4);
    }
    const int o1 = c1*4, o2 = c2*4;
    *(f32x4*)&xwlds[0][grow][o1 ^ (((o1>>6)&1)<<4)] = v1;
    if (heavy) *(f32x4*)&xwlds[0][grow][o2 ^ (((o2>>6)&1)<<4)] = v2;
  }
  float hpA = 0.f, hpB = 0.f;          // hprev for units (row1, row1+2)
  __syncthreads();

  for (int s = 0; s < 512; ++s){
    const int par = s & 1;

    // D) hw = (h_hi + h_lo) @ Wh : 96 MFMAs/wave over 6 owned col-tiles
    f32x4 acc[6];
    #pragma unroll
    for (int i=0; i<6; ++i) acc[i] = (f32x4){0.f,0.f,0.f,0.f};
    #pragma unroll
    for (int q=0; q<8; ++q){
      const int kb = q*32 + l4*8;
      const int kz = ((q>>1)&1)<<5;
      const s16x8 ahi = *(const s16x8*)&hbuf[(par*8 +     (l15&3))*272 + (kb ^ kz)];
      const s16x8 alo = *(const s16x8*)&hbuf[(par*8 + 4 + (l15&3))*272 + (kb ^ kz)];
      #pragma unroll
      for (int i=0; i<6; ++i)
        acc[i] = __builtin_amdgcn_mfma_f32_16x16x32_bf16(ahi, Bf[i][q], acc[i], 0,0,0);
      #pragma unroll
      for (int i=0; i<6; ++i)
        acc[i] = __builtin_amdgcn_mfma_f32_16x16x32_bf16(alo, Bf[i][q], acc[i], 0,0,0);
    }
    // publish hw (rows 0..3 valid in l4==0 lanes)
    if (l4 == 0){
      #pragma unroll
      for (int i=0; i<6; ++i){
        const int col = (wv*6 + i)*16 + l15;
        const int sw  = ((col>>6)&1)<<4;
        #pragma unroll
        for (int p=0; p<4; ++p)
          hwlds[p][col ^ sw] = acc[i][p];
      }
    }
    __syncthreads();                              // bar0: hwlds ready

    // A) gather xw(s+1): issued here so n1/n2 don't overlap acc[6] live range;
    //    L2 latency hides under the gates phase below.
    f32x4 n1, n2;
    if (s < 511){
      n1 = *(const f32x4*)(beff + c1*4);
      n2 = heavy ? *(const f32x4*)(beff + c2*4) : (f32x4){0.f,0.f,0.f,0.f};
      #pragma unroll
      for (int d=0; d<5; ++d){
        const int t = s - 1 + d;                  // (s+1)+d-2
        if ((unsigned)t < 512u){
          const int ch = X[bbase + t] & 127;
          const float* tp = embw + (size_t)(d*128 + ch)*768;
          n1 += *(const f32x4*)(tp + c1*4);
          if (heavy) n2 += *(const f32x4*)(tp + c2*4);
        }
      }
    }

    // E) gates: 2 units/thread: (row1, hcol), (row1+2, hcol)
    float hnA, hnB;
    #pragma unroll
    for (int u=0; u<2; ++u){
      const int row = row1 + u*2;
      const float hz = hwlds[row][(      hcol) ^ gsw] + br0;
      const float hr = hwlds[row][(256 + hcol) ^ gsw] + br1;
      const float hh = hwlds[row][(512 + hcol) ^ gsw] + br2;
      const float xz = xwlds[par][row][(      hcol) ^ gsw];
      const float xr = xwlds[par][row][(256 + hcol) ^ gsw];
      const float xh = xwlds[par][row][(512 + hcol) ^ gsw];
      const float hp = u ? hpB : hpA;
      const float z  = 1.f/(1.f + __expf(-(xz + hz)));
      const float r  = 1.f/(1.f + __expf(-(xr + hr)));
      const float pre = xh + r*hh;
      const float e2  = __expf(-2.f*fabsf(pre));
      const float th  = __builtin_copysignf((1.f - e2)/(1.f + e2), pre);
      const float hn  = z*hp + (1.f - z)*th;
      if (u) hnB = hn; else hnA = hn;
    }
    hpA = hnA; hpB = hnB;

    // F) publish h (split-bf16) to parity par^1, or final output
    if (s == 511){
      const int idx = (g*4 + row1)*256 + hcol;
      if (md){ ((float*)outv)[idx] = hnA; ((float*)outv)[idx + 512] = hnB; }
      else   { ((u16*)outv)[idx] = f2bf(hnA); ((u16*)outv)[idx + 512] = f2bf(hnB); }
    } else {
      const int pb = (par^1)*8;
      #pragma unroll
      for (int u=0; u<2; ++u){
        const int row = row1 + u*2;
        const float hn = u ? hnB : hnA;
        const u16 bh = f2bf(hn);
        const u16 bl = f2bf(hn - bf2f(bh));
        hbuf[(pb     + row)*272 + (hcol ^ ksw)] = bh;
        hbuf[(pb + 4 + row)*272 + (hcol ^ ksw)] = bl;
      }
      // W) xw(s+1) -> other buffer
      const int o1 = c1*4, o2 = c2*4;
      *(f32x4*)&xwlds[par^1][grow][o1 ^ (((o1>>6)&1)<<4)] = n1;
      if (heavy) *(f32x4*)&xwlds[par^1][grow][o2 ^ (((o2>>6)&1)<<4)] = n2;
    }
    __syncthreads();                              // bar1: h(s+1), xw(s+1) ready
  }
}

extern "C" void kernel_launch(void* const* d_in, const int* in_sizes, int n_in,
                              void* d_out, int out_size, void* d_ws, size_t ws_size,
                              hipStream_t stream){
  const int* X = (const int*)d_in[0];
  char* ws = (char*)d_ws;
  if (ws_size < WS_NEED) return;

  k_probe<<<  1,  64, 0, stream>>>(d_in[1], ws);
  k_wc   <<<320, 256, 0, stream>>>(d_in[2], d_in[4], d_in[6], d_in[8], d_in[10], ws);
  k_beff <<<  3, 256, 0, stream>>>(d_in[3], d_in[5], d_in[7], d_in[9], d_in[10], d_in[12], ws);
  k_embw <<<640, 256, 0, stream>>>(d_in[1], ws);
  k_whp  <<<768, 256, 0, stream>>>(d_in[11], ws);
  k_gru  <<< 32, 512, 0, stream>>>(X, d_in[13], ws, d_out);
}

// Round 9
// 2349.737 us; speedup vs baseline: 1.0393x; 1.0393x over previous
//
#include <hip/hip_runtime.h>
#include <hip/hip_bf16.h>

// ---------------------------------------------------------------------------
// CharRNN: emb -> 4x conv1d(SAME) -> concat -> GRU(256) last state.
//
// xw[b,t,:] = beff + sum_{d=0..4} EmbW[d][X[b,t+d-2]][:]   (f32 tables in ws)
//
// R9: fit under the observed 128-VGPR budget AND remove the 4x replicated-A
// MFMA waste. 32 blocks = 8 groups (16 real batch rows) x 4 h-col slices.
// Block: 512 thr / 8 waves = 4 col-subtiles x 2 K-halves -> Bf = 48 VGPRs.
// h exchanged cross-block via ws (packed u32 hi|lo bf16) using relaxed
// agent-scope atomics (bypass non-coherent XCD L2s; no L2-invalidating
// fences) + per-group flags (release add after vmcnt-draining barrier).
// h staged to LDS for ds_read_b128 A-frags (low reg pressure).
// Numerics = R5 (split-bf16 h, f32 tables, bf16 Wh): absmax 9.8e-4.
// ---------------------------------------------------------------------------

typedef float f32x4 __attribute__((ext_vector_type(4)));
typedef short s16x8 __attribute__((ext_vector_type(8)));
typedef int   i32x4 __attribute__((ext_vector_type(4)));
typedef unsigned short u16;
typedef unsigned int   u32;
typedef unsigned long long u64;

// ws byte offsets
#define OFF_WC    0u         // f32  [5][64][768]
#define OFF_EMBW  983040u    // f32  [5][128][768]
#define OFF_BEFF  2949120u   // f32  [768]
#define OFF_WHP   2952192u   // bf16 [768][256] (Wh^T)
#define OFF_MODE  3345408u   // int
#define OFF_HGP   3345472u   // u32 [2][8][16][256]  (par, group, row, hcol)
#define OFF_FLAG  3607616u   // int [8][516]
#define FS        516
#define WS_NEED   3624128u

__device__ __forceinline__ float bf2f(u16 v){
  unsigned u = ((unsigned)v) << 16; return __builtin_bit_cast(float, u);
}
__device__ __forceinline__ u16 f2bf(float f){
  unsigned u = __builtin_bit_cast(unsigned, f);
  unsigned r = u + 0x7FFFu + ((u >> 16) & 1u);
  return (u16)(r >> 16);
}
__device__ __forceinline__ float ldv(const void* p, int i, int m){
  return m ? ((const float*)p)[i] : bf2f(((const u16*)p)[i]);
}

// ---- init: zero phase-0 h, init flags (flag[g][0]=4 releases step 0) ----
__global__ void k_init(char* ws){
  int idx = blockIdx.x*256 + threadIdx.x;
  u32* hg = (u32*)(ws + OFF_HGP);
  if (idx < 65536) hg[idx] = 0u;                 // phase-0 plane
  int* fl = (int*)(ws + OFF_FLAG);
  if (idx < 8*FS) fl[idx] = ((idx % FS) == 0) ? 4 : 0;
}

// ---- probe: detect storage dtype of emb_table ----
__global__ void k_probe(const void* __restrict__ emb, char* ws){
  const u16* w = (const u16*)emb;
  const int ln = threadIdx.x;
  bool bad = false;
  for (int j = 0; j < 8; ++j){
    u16 v = w[ln*8 + j];
    if (((v >> 7) & 0xFF) >= 0x86) bad = true;
  }
  unsigned long long m = __ballot(bad);
  if (ln == 0) *(int*)(ws + OFF_MODE) = (__popcll(m) > 4) ? 1 : 0;
}

// ---- Wc[d][e][j] = sum_br sum_c w_br[d-2+pad][e][c] * Wx[off_br+c][j] ----
__global__ void k_wc(const void* __restrict__ w2, const void* __restrict__ w3,
                     const void* __restrict__ w4, const void* __restrict__ w5,
                     const void* __restrict__ Wx, char* ws){
  const int md = *(const int*)(ws + OFF_MODE);
  const int d = blockIdx.x >> 6;
  const int e = blockIdx.x & 63;
  const int j0 = threadIdx.x;
  const void* wv[4] = {w2,w3,w4,w5};
  const int Kk[4] = {2,3,4,5}, pd[4] = {0,1,1,2};
  float a0=0.f, a1=0.f, a2=0.f;
  for (int br=0; br<4; ++br){
    int k = d - 2 + pd[br];
    if (k < 0 || k >= Kk[br]) continue;
    const int wbase  = (k*64 + e)*128;
    const int wxbase = (br*128)*768;
    for (int c=0; c<128; ++c){
      float wcv = ldv(wv[br], wbase + c, md);
      a0 += wcv * ldv(Wx, wxbase + c*768 + j0      , md);
      a1 += wcv * ldv(Wx, wxbase + c*768 + j0 + 256, md);
      a2 += wcv * ldv(Wx, wxbase + c*768 + j0 + 512, md);
    }
  }
  float* o = (float*)(ws + OFF_WC) + (d*64 + e)*768;
  o[j0] = a0; o[j0+256] = a1; o[j0+512] = a2;
}

// ---- beff[j] = b_in[j] + sum_br sum_c b_br[c]*Wx[off+c][j] ----
__global__ void k_beff(const void* __restrict__ b2, const void* __restrict__ b3,
                       const void* __restrict__ b4, const void* __restrict__ b5,
                       const void* __restrict__ Wx, const void* __restrict__ bin,
                       char* ws){
  const int md = *(const int*)(ws + OFF_MODE);
  int j = blockIdx.x*256 + threadIdx.x;
  if (j >= 768) return;
  const void* bv[4] = {b2,b3,b4,b5};
  float acc = ldv(bin, j, md);
  for (int br=0; br<4; ++br)
    for (int c=0; c<128; ++c)
      acc += ldv(bv[br], c, md) * ldv(Wx, (br*128 + c)*768 + j, md);
  ((float*)(ws + OFF_BEFF))[j] = acc;
}

// ---- EmbW[d][ch][j] = sum_e emb[ch][e] * Wc[d][e][j]  (f32 out) ----
__global__ void k_embw(const void* __restrict__ emb, char* ws){
  const int md = *(const int*)(ws + OFF_MODE);
  const int d = blockIdx.x >> 7, ch = blockIdx.x & 127;
  const float* wc = (const float*)(ws + OFF_WC) + d*64*768;
  float* ew = (float*)(ws + OFF_EMBW) + (size_t)(d*128 + ch)*768;
  const int j0 = threadIdx.x;
  float a0=0.f, a1=0.f, a2=0.f;
  for (int e=0; e<64; ++e){
    float ev = ldv(emb, ch*64 + e, md);
    a0 += ev*wc[e*768 + j0      ];
    a1 += ev*wc[e*768 + j0 + 256];
    a2 += ev*wc[e*768 + j0 + 512];
  }
  ew[j0] = a0; ew[j0+256] = a1; ew[j0+512] = a2;
}

// ---- whp[j][k] = Wh[k][j]  (bf16 out) ----
__global__ void k_whp(const void* __restrict__ Wh, char* ws){
  const int md = *(const int*)(ws + OFF_MODE);
  const int j = blockIdx.x, k = threadIdx.x;
  ((u16*)(ws + OFF_WHP))[j*256 + k] = f2bf(ldv(Wh, k*768 + j, md));
}

// ---- GRU: 32 blocks = 8 groups x 4 slices; 512 thr / 8 waves ----
__launch_bounds__(512, 1)
__global__ void k_gru(const int* __restrict__ X, const void* __restrict__ brec,
                      char* __restrict__ ws, void* __restrict__ outv){
  const int tid = threadIdx.x;
  const int w   = tid >> 6, ln = tid & 63;
  const int l15 = ln & 15, l4 = ln >> 4;
  const int g = blockIdx.x >> 2, r = blockIdx.x & 3;

  const int md = *(const int*)(ws + OFF_MODE);
  const float* embw = (const float*)(ws + OFF_EMBW);
  const float* beff = (const float*)(ws + OFF_BEFF);
  const u16*   whp  = (const u16*)(ws + OFF_WHP);
  u32* hgp = (u32*)(ws + OFF_HGP);
  int* flg = (int*)(ws + OFF_FLAG) + g*FS;

  __shared__ int   Xs[16*512];           // 32 KB: group's token rows
  __shared__ float xwlds[2][16][196];    // 25 KB: block's 192 gate cols, dbuf
  __shared__ float hwp[2][16][196];      // 25 KB: partial hw per K-half
  __shared__ u16   hstage[2][16][272];   // 17 KB: staged h hi/lo planes

  // stage X
  for (int i = tid; i < 2048; i += 512)
    ((i32x4*)Xs)[i] = ((const i32x4*)(X + g*16*512))[i];

  // persistent Wh B-frags: wave w -> subtile w&3, K-half w>>2
  const int qs = (w >> 2) * 4;
  s16x8 Bf[3][4];
  #pragma unroll
  for (int gg=0; gg<3; ++gg){
    const int col = gg*256 + r*64 + (w&3)*16 + l15;
    #pragma unroll
    for (int qi=0; qi<4; ++qi)
      Bf[gg][qi] = *(const s16x8*)(whp + col*256 + (qs+qi)*32 + l4*8);
  }

  // gates assignment: thread -> h-col c63 = r*64+(tid&63), rows tr, tr+8
  const int c63 = tid & 63;
  const int tr  = (tid >> 6) & 7;
  const int hc  = r*64 + c63;
  const float br0 = ldv(brec,       hc, md);
  const float br1 = ldv(brec, 256 + hc, md);
  const float br2 = ldv(brec, 512 + hc, md);

  // gather assignment: chunk ids cid1 = tid, cid2 = tid+512 (tid<256 only)
  // cid -> row=cid/48, gg=(cid%48)/16, cc=(cid%48)%16 -> 4 f32 at gate col
  const int row1 = tid / 48,      rem1 = tid % 48;
  const int gg1  = rem1 / 16,     cc1  = rem1 % 16;
  const int cid2 = tid + 512;
  const int row2 = cid2 / 48,     rem2 = cid2 % 48;
  const int gg2  = rem2 / 16,     cc2  = rem2 % 16;
  const bool two = (tid < 256);
  const int gcol1 = gg1*256 + r*64 + cc1*4;
  const int gcol2 = gg2*256 + r*64 + cc2*4;
  const f32x4 be1 = *(const f32x4*)(beff + gcol1);
  const f32x4 be2 = *(const f32x4*)(beff + gcol2);

  // h-stage assignment: thread -> row srow=tid>>5, 8 packed cols sc0
  const int srow = tid >> 5, sc0 = (tid & 31) * 8;

  __syncthreads();   // Xs staged before any Xs read

  // prologue: xw(0) -> xwlds[0]   (t = 0 + d - 2)
  {
    f32x4 v1 = be1, v2 = be2;
    #pragma unroll
    for (int d=0; d<5; ++d){
      const int t = d - 2;
      if ((unsigned)t < 512u){
        const int ch1 = Xs[row1*512 + t] & 127;
        v1 += *(const f32x4*)(embw + (size_t)(d*128 + ch1)*768 + gcol1);
        if (two){
          const int ch2 = Xs[row2*512 + t] & 127;
          v2 += *(const f32x4*)(embw + (size_t)(d*128 + ch2)*768 + gcol2);
        }
      }
    }
    *(f32x4*)&xwlds[0][row1][gg1*64 + cc1*4] = v1;
    if (two) *(f32x4*)&xwlds[0][row2][gg2*64 + cc2*4] = v2;
  }
  float hpA = 0.f, hpB = 0.f;
  __syncthreads();

  for (int s = 0; s < 512; ++s){
    const int par = s & 1;

    // S0) wait for all 4 slice-producers of step s
    {
      int guard = 0;
      while (__hip_atomic_load(&flg[s], __ATOMIC_RELAXED, __HIP_MEMORY_SCOPE_AGENT) < 4){
        if (++guard > (1<<23)) break;   // fail visibly, never hang
      }
    }

    // S1) load h (packed u32, agent-coherent) and stage to LDS planes
    {
      const u32* hb = hgp + (unsigned)par*32768u + (unsigned)g*4096u
                      + (unsigned)srow*256u + (unsigned)sc0;
      u64 d0 = __hip_atomic_load((const u64*)hb+0, __ATOMIC_RELAXED, __HIP_MEMORY_SCOPE_AGENT);
      u64 d1 = __hip_atomic_load((const u64*)hb+1, __ATOMIC_RELAXED, __HIP_MEMORY_SCOPE_AGENT);
      u64 d2 = __hip_atomic_load((const u64*)hb+2, __ATOMIC_RELAXED, __HIP_MEMORY_SCOPE_AGENT);
      u64 d3 = __hip_atomic_load((const u64*)hb+3, __ATOMIC_RELAXED, __HIP_MEMORY_SCOPE_AGENT);
      u32 wd[8] = {(u32)d0,(u32)(d0>>32),(u32)d1,(u32)(d1>>32),
                   (u32)d2,(u32)(d2>>32),(u32)d3,(u32)(d3>>32)};
      s16x8 hi, lo;
      #pragma unroll
      for (int j=0; j<8; ++j){ hi[j] = (short)(wd[j] & 0xFFFFu); lo[j] = (short)(wd[j] >> 16); }
      *(s16x8*)&hstage[0][srow][sc0] = hi;
      *(s16x8*)&hstage[1][srow][sc0] = lo;
    }
    __syncthreads();                          // barA: stage ready

    // S2) partial hw over this wave's K-half: 24 MFMAs
    f32x4 a0 = {0.f,0.f,0.f,0.f}, a1 = a0, a2 = a0;
    #pragma unroll
    for (int qi=0; qi<4; ++qi){
      const int kb = (qs+qi)*32 + l4*8;
      const s16x8 ahi = *(const s16x8*)&hstage[0][l15][kb];
      const s16x8 alo = *(const s16x8*)&hstage[1][l15][kb];
      a0 = __builtin_amdgcn_mfma_f32_16x16x32_bf16(ahi, Bf[0][qi], a0, 0,0,0);
      a1 = __builtin_amdgcn_mfma_f32_16x16x32_bf16(ahi, Bf[1][qi], a1, 0,0,0);
      a2 = __builtin_amdgcn_mfma_f32_16x16x32_bf16(ahi, Bf[2][qi], a2, 0,0,0);
      a0 = __builtin_amdgcn_mfma_f32_16x16x32_bf16(alo, Bf[0][qi], a0, 0,0,0);
      a1 = __builtin_amdgcn_mfma_f32_16x16x32_bf16(alo, Bf[1][qi], a1, 0,0,0);
      a2 = __builtin_amdgcn_mfma_f32_16x16x32_bf16(alo, Bf[2][qi], a2, 0,0,0);
    }
    // write partials: D row = l4*4+p, col subtile (w&3)*16+l15
    {
      const int kh = w >> 2, sc = (w&3)*16 + l15;
      #pragma unroll
      for (int p=0; p<4; ++p){
        hwp[kh][l4*4+p][       sc] = a0[p];
        hwp[kh][l4*4+p][ 64 + sc] = a1[p];
        hwp[kh][l4*4+p][128 + sc] = a2[p];
      }
    }

    // S3) gather xw(s+1): issue now, consumed after gates (latency hidden)
    f32x4 n1, n2;
    if (s < 511){
      n1 = be1; n2 = be2;
      #pragma unroll
      for (int d=0; d<5; ++d){
        const int t = s - 1 + d;
        if ((unsigned)t < 512u){
          const int ch1 = Xs[row1*512 + t] & 127;
          n1 += *(const f32x4*)(embw + (size_t)(d*128 + ch1)*768 + gcol1);
          if (two){
            const int ch2 = Xs[row2*512 + t] & 127;
            n2 += *(const f32x4*)(embw + (size_t)(d*128 + ch2)*768 + gcol2);
          }
        }
      }
    }
    __syncthreads();                          // barB: hwp ready

    // S4) gates for units (tr, hc) and (tr+8, hc)
    float hnA, hnB;
    #pragma unroll
    for (int u=0; u<2; ++u){
      const int row = tr + u*8;
      const float hz = hwp[0][row][      c63] + hwp[1][row][      c63] + br0;
      const float hr = hwp[0][row][ 64 + c63] + hwp[1][row][ 64 + c63] + br1;
      const float hh = hwp[0][row][128 + c63] + hwp[1][row][128 + c63] + br2;
      const float xz = xwlds[par][row][      c63];
      const float xr = xwlds[par][row][ 64 + c63];
      const float xh = xwlds[par][row][128 + c63];
      const float hp = u ? hpB : hpA;
      const float z  = 1.f/(1.f + __expf(-(xz + hz)));
      const float rg = 1.f/(1.f + __expf(-(xr + hr)));
      const float pre = xh + rg*hh;
      const float e2  = __expf(-2.f*fabsf(pre));
      const float th  = __builtin_copysignf((1.f - e2)/(1.f + e2), pre);
      const float hn  = z*hp + (1.f - z)*th;
      if (u) hnB = hn; else hnA = hn;
    }
    hpA = hnA; hpB = hnB;

    // S5) publish h (packed hi|lo) via agent atomics, or final output
    if (s == 511){
      const int i0 = (g*16 + tr)*256 + hc;
      if (md){ ((float*)outv)[i0] = hnA; ((float*)outv)[i0 + 8*256] = hnB; }
      else   { ((u16*)outv)[i0] = f2bf(hnA); ((u16*)outv)[i0 + 8*256] = f2bf(hnB); }
    } else {
      u32* hb = hgp + (unsigned)(par^1)*32768u + (unsigned)g*4096u;
      #pragma unroll
      for (int u=0; u<2; ++u){
        const float hn = u ? hnB : hnA;
        const u32 bh = f2bf(hn);
        const u32 bl = f2bf(hn - bf2f((u16)bh));
        __hip_atomic_store(hb + (tr + u*8)*256 + hc, bh | (bl << 16),
                           __ATOMIC_RELAXED, __HIP_MEMORY_SCOPE_AGENT);
      }
      // xw(s+1) -> other buffer
      *(f32x4*)&xwlds[par^1][row1][gg1*64 + cc1*4] = n1;
      if (two) *(f32x4*)&xwlds[par^1][row2][gg2*64 + cc2*4] = n2;
    }

    // S6) drain (barrier waits vmcnt) then release-signal step s+1
    __syncthreads();
    if (s < 511 && tid == 0)
      __hip_atomic_fetch_add(&flg[s+1], 1, __ATOMIC_RELEASE, __HIP_MEMORY_SCOPE_AGENT);
  }
}

extern "C" void kernel_launch(void* const* d_in, const int* in_sizes, int n_in,
                              void* d_out, int out_size, void* d_ws, size_t ws_size,
                              hipStream_t stream){
  const int* X = (const int*)d_in[0];
  char* ws = (char*)d_ws;
  if (ws_size < WS_NEED) return;

  k_init <<<288, 256, 0, stream>>>(ws);
  k_probe<<<  1,  64, 0, stream>>>(d_in[1], ws);
  k_wc   <<<320, 256, 0, stream>>>(d_in[2], d_in[4], d_in[6], d_in[8], d_in[10], ws);
  k_beff <<<  3, 256, 0, stream>>>(d_in[3], d_in[5], d_in[7], d_in[9], d_in[10], d_in[12], ws);
  k_embw <<<640, 256, 0, stream>>>(d_in[1], ws);
  k_whp  <<<768, 256, 0, stream>>>(d_in[11], ws);
  k_gru  <<< 32, 512, 0, stream>>>(X, d_in[13], ws, d_out);
}